// Round 1
// baseline (2204.228 us; speedup 1.0000x reference)
//
#include <hip/hip_runtime.h>
#include <stdint.h>

#define NR 131072
#define DD 512
#define KC 1024
#define ALPHA 32.0f
#define EPSV 1e-5f

typedef __attribute__((ext_vector_type(8))) short bf16x8;
typedef __attribute__((ext_vector_type(4))) float f32x4;

typedef const __attribute__((address_space(1))) void* gas_p;
typedef __attribute__((address_space(3))) void* las_p;

__device__ __forceinline__ void gld_lds16(const void* g, void* l) {
    __builtin_amdgcn_global_load_lds((gas_p)g, (las_p)l, 16, 0, 0);
}

__device__ __forceinline__ unsigned short f2bf(float f) {
    unsigned u = __float_as_uint(f);
    u += 0x7FFFu + ((u >> 16) & 1u);   // RNE
    return (unsigned short)(u >> 16);
}
__device__ __forceinline__ float bf2f(unsigned short h) {
    return __uint_as_float(((unsigned)h) << 16);
}

// ---------------- prep centers: split bf16 + transposed copy + |c|^2 ----------------
__global__ __launch_bounds__(256) void prep_centers(
        const float* __restrict__ cc,
        unsigned short* __restrict__ chp, unsigned short* __restrict__ clp,
        unsigned short* __restrict__ ctp, float* __restrict__ c2) {
    int k = blockIdx.x;      // 1024 clusters
    int t = threadIdx.x;     // 256
    float s = 0.f;
    #pragma unroll
    for (int i = 0; i < 2; ++i) {
        int d = t + i * 256;
        float v = cc[k * DD + d];
        unsigned short h = f2bf(v);
        chp[k * DD + d] = h;
        clp[k * DD + d] = f2bf(v - bf2f(h));
        ctp[d * KC + k] = h;                 // C^T for the second GEMM
        s += v * v;
    }
    __shared__ float red[256];
    red[t] = s; __syncthreads();
    for (int o = 128; o > 0; o >>= 1) { if (t < o) red[t] += red[t + o]; __syncthreads(); }
    if (t == 0) c2[k] = red[0];
}

// ---------------- layernorm: one wave per row; writes split-bf16 xn, |xn|^2, dmin=inf ----------------
__global__ __launch_bounds__(256) void ln_kernel(
        const float* __restrict__ x, const float* __restrict__ gam, const float* __restrict__ bet,
        unsigned short* __restrict__ xh, unsigned short* __restrict__ xl,
        float* __restrict__ x2, unsigned int* __restrict__ dmin) {
    int wv = threadIdx.x >> 6, ln = threadIdx.x & 63;
    long row = (long)blockIdx.x * 4 + wv;
    const float4* px = (const float4*)(x + row * DD);
    float4 a = px[ln], b = px[ln + 64];
    float v[8] = {a.x, a.y, a.z, a.w, b.x, b.y, b.z, b.w};
    float s = 0.f;
    #pragma unroll
    for (int i = 0; i < 8; ++i) s += v[i];
    #pragma unroll
    for (int o = 32; o; o >>= 1) s += __shfl_xor(s, o, 64);
    float mean = s * (1.f / 512.f);
    float vs = 0.f;
    #pragma unroll
    for (int i = 0; i < 8; ++i) { float t = v[i] - mean; vs += t * t; }
    #pragma unroll
    for (int o = 32; o; o >>= 1) vs += __shfl_xor(vs, o, 64);
    float inv = 1.f / (sqrtf(vs * (1.f / 512.f)) + EPSV);   // (x-mean)/(std+eps)
    const float4* pg = (const float4*)gam;
    const float4* pb = (const float4*)bet;
    float4 g0 = pg[ln], g1 = pg[ln + 64], b0 = pb[ln], b1 = pb[ln + 64];
    float gg[8] = {g0.x, g0.y, g0.z, g0.w, g1.x, g1.y, g1.z, g1.w};
    float bb[8] = {b0.x, b0.y, b0.z, b0.w, b1.x, b1.y, b1.z, b1.w};
    float xn[8]; float s2 = 0.f;
    #pragma unroll
    for (int i = 0; i < 8; ++i) {
        xn[i] = (v[i] - mean) * inv * gg[i] + bb[i];
        s2 += xn[i] * xn[i];
    }
    #pragma unroll
    for (int o = 32; o; o >>= 1) s2 += __shfl_xor(s2, o, 64);
    ushort4 h0, h1, l0, l1;
    h0.x = f2bf(xn[0]); h0.y = f2bf(xn[1]); h0.z = f2bf(xn[2]); h0.w = f2bf(xn[3]);
    h1.x = f2bf(xn[4]); h1.y = f2bf(xn[5]); h1.z = f2bf(xn[6]); h1.w = f2bf(xn[7]);
    l0.x = f2bf(xn[0] - bf2f(h0.x)); l0.y = f2bf(xn[1] - bf2f(h0.y));
    l0.z = f2bf(xn[2] - bf2f(h0.z)); l0.w = f2bf(xn[3] - bf2f(h0.w));
    l1.x = f2bf(xn[4] - bf2f(h1.x)); l1.y = f2bf(xn[5] - bf2f(h1.y));
    l1.z = f2bf(xn[6] - bf2f(h1.z)); l1.w = f2bf(xn[7] - bf2f(h1.w));
    *(ushort4*)(xh + row * DD + ln * 4)       = h0;
    *(ushort4*)(xh + row * DD + 256 + ln * 4) = h1;
    *(ushort4*)(xl + row * DD + ln * 4)       = l0;
    *(ushort4*)(xl + row * DD + 256 + ln * 4) = l1;
    if (ln == 0) { x2[row] = s2; dmin[row] = 0x7F800000u; }  // +inf bits
}

// ---------------- GEMM1: dist = sqrt(x2 + c2 - 2*xn.c^T), split-bf16 (3 MFMAs), rowmin atomics ----------------
// 128x128 tile, BK=32, 256 thr. XOR chunk swizzle baked into staging source addresses.
__global__ __launch_bounds__(256, 2) void gemm_dist(
        const unsigned short* __restrict__ xh, const unsigned short* __restrict__ xl,
        const unsigned short* __restrict__ chp, const unsigned short* __restrict__ clp,
        const float* __restrict__ x2, const float* __restrict__ c2,
        float* __restrict__ dist, unsigned int* __restrict__ dmin) {
    __shared__ __align__(16) unsigned short sAh[128 * 32], sAl[128 * 32];
    __shared__ __align__(16) unsigned short sBh[128 * 32], sBl[128 * 32];
    int bid = blockIdx.x;
    int slot = bid >> 3;
    long rowBase = ((long)(bid & 7) * 128 + (slot >> 3)) * 128;  // XCD-swizzled: 8 col-tiles of a row-tile share an XCD
    int colBase = (slot & 7) * 128;
    int tid = threadIdx.x;
    int ln = tid & 63;
    int wr = (tid >> 7) & 1, wc = (tid >> 6) & 1;
    int quad = ln >> 4, l16 = ln & 15;
    int wbase = tid & 192;

    f32x4 acc[4][4];
    #pragma unroll
    for (int mi = 0; mi < 4; ++mi)
        #pragma unroll
        for (int ni = 0; ni < 4; ++ni) acc[mi][ni] = (f32x4){0.f, 0.f, 0.f, 0.f};

    for (int it = 0; it < 16; ++it) {
        int k0 = it * 32;
        __syncthreads();
        #pragma unroll
        for (int i = 0; i < 2; ++i) {
            int c = i * 256 + tid;
            int r = c >> 2, sl = c & 3;
            int kk = ((sl - (r >> 1)) & 3) * 8;        // inverse bank swizzle on the source
            unsigned lofs = (unsigned)(i * 256 + wbase) * 16;
            size_t ga = (size_t)(rowBase + r) * DD + k0 + kk;
            size_t gb = (size_t)(colBase + r) * DD + k0 + kk;
            gld_lds16(xh + ga, (char*)sAh + lofs);
            gld_lds16(xl + ga, (char*)sAl + lofs);
            gld_lds16(chp + gb, (char*)sBh + lofs);
            gld_lds16(clp + gb, (char*)sBl + lofs);
        }
        __syncthreads();
        bf16x8 ah[4], al[4], bh[4], bl[4];
        #pragma unroll
        for (int mi = 0; mi < 4; ++mi) {
            int m = wr * 64 + mi * 16 + l16;
            int idx = m * 32 + ((quad + (m >> 1)) & 3) * 8;
            ah[mi] = *(const bf16x8*)&sAh[idx];
            al[mi] = *(const bf16x8*)&sAl[idx];
        }
        #pragma unroll
        for (int ni = 0; ni < 4; ++ni) {
            int n = wc * 64 + ni * 16 + l16;
            int idx = n * 32 + ((quad + (n >> 1)) & 3) * 8;
            bh[ni] = *(const bf16x8*)&sBh[idx];
            bl[ni] = *(const bf16x8*)&sBl[idx];
        }
        #pragma unroll
        for (int mi = 0; mi < 4; ++mi)
            #pragma unroll
            for (int ni = 0; ni < 4; ++ni) {
                acc[mi][ni] = __builtin_amdgcn_mfma_f32_16x16x32_bf16(ah[mi], bh[ni], acc[mi][ni], 0, 0, 0);
                acc[mi][ni] = __builtin_amdgcn_mfma_f32_16x16x32_bf16(ah[mi], bl[ni], acc[mi][ni], 0, 0, 0);
                acc[mi][ni] = __builtin_amdgcn_mfma_f32_16x16x32_bf16(al[mi], bh[ni], acc[mi][ni], 0, 0, 0);
            }
    }
    // epilogue: d2 -> dist, per-row min -> global atomicMin (uint bits, dist>=0)
    float c2v[4];
    #pragma unroll
    for (int ni = 0; ni < 4; ++ni) c2v[ni] = c2[colBase + wc * 64 + ni * 16 + l16];
    #pragma unroll
    for (int mi = 0; mi < 4; ++mi) {
        #pragma unroll
        for (int r = 0; r < 4; ++r) {
            long m = rowBase + wr * 64 + mi * 16 + quad * 4 + r;
            float xv = x2[m];
            float best = 3.4e38f;
            float* orow = dist + m * KC + colBase + wc * 64 + l16;
            #pragma unroll
            for (int ni = 0; ni < 4; ++ni) {
                float d2 = xv + c2v[ni] - 2.f * acc[mi][ni][r];
                float d = sqrtf(fmaxf(d2, 0.f));
                orow[ni * 16] = d;
                best = fminf(best, d);
            }
            #pragma unroll
            for (int o = 1; o < 16; o <<= 1) best = fminf(best, __shfl_xor(best, o, 64));
            if (l16 == 0) atomicMin(&dmin[m], __float_as_uint(best));
        }
    }
}

// ---------------- softmax over K per row: soft = exp(-alpha*(d-dmin)) / sum ----------------
__global__ __launch_bounds__(256) void softmax_k(
        const float* __restrict__ dist, const unsigned int* __restrict__ dmin,
        float* __restrict__ soft) {
    int wv = threadIdx.x >> 6, ln = threadIdx.x & 63;
    long row = (long)blockIdx.x * 4 + wv;
    float dm = __uint_as_float(dmin[row]);
    const float4* p = (const float4*)(dist + row * KC);
    float4* o = (float4*)(soft + row * KC);
    float4 v[4], e[4];
    #pragma unroll
    for (int i = 0; i < 4; ++i) v[i] = p[ln + i * 64];
    float s = 0.f;
    #pragma unroll
    for (int i = 0; i < 4; ++i) {
        e[i].x = __expf(ALPHA * (dm - v[i].x));
        e[i].y = __expf(ALPHA * (dm - v[i].y));
        e[i].z = __expf(ALPHA * (dm - v[i].z));
        e[i].w = __expf(ALPHA * (dm - v[i].w));
        s += e[i].x + e[i].y + e[i].z + e[i].w;
    }
    #pragma unroll
    for (int off = 32; off; off >>= 1) s += __shfl_xor(s, off, 64);
    float inv = 1.f / s;
    #pragma unroll
    for (int i = 0; i < 4; ++i) {
        float4 w;
        w.x = e[i].x * inv; w.y = e[i].y * inv; w.z = e[i].z * inv; w.w = e[i].w * inv;
        o[ln + i * 64] = w;
    }
}

// ---------------- GEMM2: x_rec = soft @ C  (soft fp32 -> bf16 on the fly; B = C^T bf16) ----------------
// 128x128 tile, BK=64, 256 thr.
__global__ __launch_bounds__(256, 2) void gemm_rec(
        const float* __restrict__ soft, const unsigned short* __restrict__ ctp,
        float* __restrict__ xrec) {
    __shared__ __align__(16) unsigned short sA[128 * 64], sB[128 * 64];
    int bid = blockIdx.x;
    int slot = bid >> 3;
    long rowBase = ((long)(bid & 7) * 128 + (slot >> 2)) * 128;
    int colBase = (slot & 3) * 128;
    int tid = threadIdx.x, ln = tid & 63;
    int wr = (tid >> 7) & 1, wc = (tid >> 6) & 1;
    int quad = ln >> 4, l16 = ln & 15;
    int wbase = tid & 192;

    f32x4 acc[4][4];
    #pragma unroll
    for (int mi = 0; mi < 4; ++mi)
        #pragma unroll
        for (int ni = 0; ni < 4; ++ni) acc[mi][ni] = (f32x4){0.f, 0.f, 0.f, 0.f};

    for (int it = 0; it < 16; ++it) {
        int k0 = it * 64;
        __syncthreads();
        // B tile: direct global->LDS (C^T is row-major along k)
        #pragma unroll
        for (int i = 0; i < 4; ++i) {
            int c = i * 256 + tid;
            int r = c >> 3, sl = c & 7;
            int kk = ((sl - (r >> 1)) & 7) * 8;
            gld_lds16(ctp + (size_t)(colBase + r) * KC + k0 + kk,
                      (char*)sB + (unsigned)(i * 256 + wbase) * 16);
        }
        // A tile: fp32 soft -> bf16, via registers
        #pragma unroll
        for (int i = 0; i < 4; ++i) {
            int c = i * 256 + tid;
            int r = c >> 3, sl = c & 7;
            int kk = ((sl - (r >> 1)) & 7) * 8;
            const float4* g = (const float4*)(soft + (size_t)(rowBase + r) * KC + k0 + kk);
            float4 f0 = g[0], f1 = g[1];
            bf16x8 pk;
            pk[0] = (short)f2bf(f0.x); pk[1] = (short)f2bf(f0.y);
            pk[2] = (short)f2bf(f0.z); pk[3] = (short)f2bf(f0.w);
            pk[4] = (short)f2bf(f1.x); pk[5] = (short)f2bf(f1.y);
            pk[6] = (short)f2bf(f1.z); pk[7] = (short)f2bf(f1.w);
            *(bf16x8*)&sA[r * 64 + sl * 8] = pk;
        }
        __syncthreads();
        #pragma unroll
        for (int ks = 0; ks < 2; ++ks) {
            bf16x8 af[4], bfr[4];
            #pragma unroll
            for (int mi = 0; mi < 4; ++mi) {
                int m = wr * 64 + mi * 16 + l16;
                af[mi] = *(const bf16x8*)&sA[m * 64 + ((ks * 4 + quad + (m >> 1)) & 7) * 8];
            }
            #pragma unroll
            for (int ni = 0; ni < 4; ++ni) {
                int n = wc * 64 + ni * 16 + l16;
                bfr[ni] = *(const bf16x8*)&sB[n * 64 + ((ks * 4 + quad + (n >> 1)) & 7) * 8];
            }
            #pragma unroll
            for (int mi = 0; mi < 4; ++mi)
                #pragma unroll
                for (int ni = 0; ni < 4; ++ni)
                    acc[mi][ni] = __builtin_amdgcn_mfma_f32_16x16x32_bf16(af[mi], bfr[ni], acc[mi][ni], 0, 0, 0);
        }
    }
    #pragma unroll
    for (int mi = 0; mi < 4; ++mi) {
        #pragma unroll
        for (int r = 0; r < 4; ++r) {
            long m = rowBase + wr * 64 + mi * 16 + quad * 4 + r;
            float* orow = xrec + m * DD + colBase + wc * 64 + l16;
            #pragma unroll
            for (int ni = 0; ni < 4; ++ni) orow[ni * 16] = acc[mi][ni][r];
        }
    }
}

extern "C" void kernel_launch(void* const* d_in, const int* in_sizes, int n_in,
                              void* d_out, int out_size, void* d_ws, size_t ws_size,
                              hipStream_t stream) {
    const float* x  = (const float*)d_in[0];
    const float* lw = (const float*)d_in[1];
    const float* lb = (const float*)d_in[2];
    const float* cc = (const float*)d_in[3];

    float* dist = (float*)d_out;
    float* soft = dist + (size_t)NR * KC;
    float* xrec = soft + (size_t)NR * KC;

    char* ws = (char*)d_ws;
    unsigned short* xh  = (unsigned short*)ws;  ws += (size_t)NR * DD * 2;   // 128 MiB
    unsigned short* xl  = (unsigned short*)ws;  ws += (size_t)NR * DD * 2;   // 128 MiB
    float*          x2  = (float*)ws;           ws += (size_t)NR * 4;        // 512 KiB
    unsigned int*   dmn = (unsigned int*)ws;    ws += (size_t)NR * 4;        // 512 KiB
    unsigned short* chp = (unsigned short*)ws;  ws += (size_t)KC * DD * 2;   // 1 MiB
    unsigned short* clp = (unsigned short*)ws;  ws += (size_t)KC * DD * 2;   // 1 MiB
    unsigned short* ctp = (unsigned short*)ws;  ws += (size_t)DD * KC * 2;   // 1 MiB
    float*          c2  = (float*)ws;           ws += (size_t)KC * 4;        // 4 KiB

    prep_centers<<<KC, 256, 0, stream>>>(cc, chp, clp, ctp, c2);
    ln_kernel<<<NR / 4, 256, 0, stream>>>(x, lw, lb, xh, xl, x2, dmn);
    gemm_dist<<<(NR / 128) * (KC / 128), 256, 0, stream>>>(xh, xl, chp, clp, x2, c2, dist, dmn);
    softmax_k<<<NR / 4, 256, 0, stream>>>(dist, dmn, soft);
    gemm_rec<<<(NR / 128) * (DD / 128), 256, 0, stream>>>(soft, ctp, xrec);
}